// Round 19
// baseline (252.513 us; speedup 1.0000x reference)
//
#include <hip/hip_runtime.h>

typedef __bf16 bf16;
typedef __attribute__((ext_vector_type(8))) __bf16 bf16x8;
typedef __attribute__((ext_vector_type(4))) __bf16 bf16x4;
typedef __attribute__((ext_vector_type(4))) float f32x4;

#define NBATCH 8
#define NHEAD  12
#define SEQ    2048
#define DH     64
#define CDIM   768
#define MROWS  (NBATCH*SEQ)   /* 16384 */
#define NQKV   (3*CDIM)       /* 2304  */

__device__ __forceinline__ f32x4 mfma16(bf16x8 a, bf16x8 b, f32x4 c) {
  return __builtin_amdgcn_mfma_f32_16x16x32_bf16(a, b, c, 0, 0, 0);
}

__device__ __forceinline__ void gload_lds16(const void* g, void* l) {
  __builtin_amdgcn_global_load_lds((const __attribute__((address_space(1))) void*)g,
                                   (__attribute__((address_space(3))) void*)l,
                                   16, 0, 0);
}

// pack 2 f32 -> 1 u32 of 2 bf16 (T12; no builtin on gfx950, guide m240)
__device__ __forceinline__ unsigned cvt_pk_bf16(float lo, float hi) {
  unsigned r;
  asm("v_cvt_pk_bf16_f32 %0, %1, %2" : "=v"(r) : "v"(lo), "v"(hi));
  return r;
}

// raw v_exp_f32 (2^x). Register-only asm; args always <= 0 after first rescale.
__device__ __forceinline__ float exp2_raw(float x) {
  float r;
  asm("v_exp_f32 %0, %1" : "=v"(r) : "v"(x));
  return r;
}

// ---------------- fp32 -> bf16 convert (all three inputs, one launch) -----
__global__ __launch_bounds__(256)
void cvt_all(const float* __restrict__ x, const float* __restrict__ wq,
             const float* __restrict__ wp, bf16* __restrict__ xd,
             bf16* __restrict__ wqd, bf16* __restrict__ wpd) {
  const int bid = blockIdx.x;
  const float* s;
  bf16* d;
  int i;
  if (bid < 6144)      { s = x;  d = xd;  i = bid * 256 + threadIdx.x; }
  else if (bid < 7008) { s = wq; d = wqd; i = (bid - 6144) * 256 + threadIdx.x; }
  else                 { s = wp; d = wpd; i = (bid - 7008) * 256 + threadIdx.x; }
  const float4* s4 = (const float4*)s;
  float4 a = s4[2*i], c = s4[2*i+1];
  bf16x8 o;
  o[0]=(bf16)a.x; o[1]=(bf16)a.y; o[2]=(bf16)a.z; o[3]=(bf16)a.w;
  o[4]=(bf16)c.x; o[5]=(bf16)c.y; o[6]=(bf16)c.z; o[7]=(bf16)c.w;
  *(bf16x8*)(d + (size_t)i*8) = o;
}

// ---------------- GEMM 128x128 / BK=32, 3-buf single-barrier pipeline -----
// R18 structure; tile-group swizzle reduced 32->16 tm-tiles/group so a
// group's A-panel slice (16x128 rows x 768 x 2B = 3MB) fits the 4MB per-XCD
// L2 (32-tile groups were 6MB -> thrash across the tn sweep).
// V-section tiles (n0>=1536) write transposed into Vt (R17 fusion, proven).
template <int OUT_F32>
__global__ __launch_bounds__(256, 3)
void gemm_bt(const bf16* __restrict__ A, const bf16* __restrict__ Bm,
             void* __restrict__ Cout, const float* __restrict__ bias,
             bf16* __restrict__ Vt, int M, int Nn, int K) {
  __shared__ bf16 As[3][4096];
  __shared__ bf16 Bs[3][4096];
  const int tid = threadIdx.x, wid = tid >> 6, lane = tid & 63;
  const int g = lane >> 4, ln = lane & 15;
  const int ntn = Nn >> 7;
  const int gsz = 16 * ntn;
  const int grp = blockIdx.x / gsz;
  const int rem = blockIdx.x - grp * gsz;
  const int tm = grp * 16 + (rem & 15);
  const int tn = rem >> 4;
  const int m0 = tm << 7, n0 = tn << 7;
  const int wr = wid >> 1, wc = wid & 1;

  const int srow = lane >> 2;
  const int sslot = lane & 3;
  const int c0 = wid * 2, c1 = wid * 2 + 1;
  const int row0 = c0 * 16 + srow, row1 = c1 * 16 + srow;
  const int sw0 = (sslot ^ (row0 & 3)) << 3;
  const int sw1 = (sslot ^ (row1 & 3)) << 3;
  const bf16* a0 = A + (size_t)(m0 + row0) * K + sw0;
  const bf16* a1 = A + (size_t)(m0 + row1) * K + sw1;
  const bf16* b0 = Bm + (size_t)(n0 + row0) * K + sw0;
  const bf16* b1 = Bm + (size_t)(n0 + row1) * K + sw1;

  f32x4 acc[4][4] = {};
  const int nkt = K >> 5;

#define GSTAGE(BUF) do {                                          \
    gload_lds16(a0, &As[BUF][c0 * 512]);                          \
    gload_lds16(a1, &As[BUF][c1 * 512]);                          \
    gload_lds16(b0, &Bs[BUF][c0 * 512]);                          \
    gload_lds16(b1, &Bs[BUF][c1 * 512]);                          \
    a0 += 32; a1 += 32; b0 += 32; b1 += 32;                       \
  } while (0)

  GSTAGE(0);
  GSTAGE(1);

  int cur = 0;
  for (int kt = 0; kt < nkt; ++kt) {
    if (kt < nkt - 1) asm volatile("s_waitcnt vmcnt(4)" ::: "memory");
    else              asm volatile("s_waitcnt vmcnt(0)" ::: "memory");
    __builtin_amdgcn_s_barrier();
    __builtin_amdgcn_sched_barrier(0);

    if (kt + 2 < nkt) {
      int sb = cur + 2; if (sb >= 3) sb -= 3;
      GSTAGE(sb);
    }

    const bf16* AsB = &As[cur][0];
    const bf16* BsB = &Bs[cur][0];
    bf16x8 aF[4], bF[4];
    #pragma unroll
    for (int m = 0; m < 4; ++m) {
      int row = wr * 64 + m * 16 + ln;
      aF[m] = *(const bf16x8*)&AsB[row * 32 + ((g ^ (row & 3)) << 3)];
    }
    #pragma unroll
    for (int n = 0; n < 4; ++n) {
      int row = wc * 64 + n * 16 + ln;
      bF[n] = *(const bf16x8*)&BsB[row * 32 + ((g ^ (row & 3)) << 3)];
    }
    #pragma unroll
    for (int m = 0; m < 4; ++m)
      #pragma unroll
      for (int n = 0; n < 4; ++n)
        acc[m][n] = mfma16(aF[m], bF[n], acc[m][n]);

    cur = (cur + 1 == 3) ? 0 : cur + 1;
  }
#undef GSTAGE

  if (!OUT_F32 && n0 >= 2 * CDIM) {
    // V-tile: write transposed into Vt [b*768 + dglobal][npos] (stride SEQ)
    const int b = m0 >> 11;
    const int npos0 = m0 & (SEQ - 1);
    #pragma unroll
    for (int m = 0; m < 4; ++m) {
      const int npos = npos0 + wr * 64 + m * 16 + g * 4;
      #pragma unroll
      for (int n = 0; n < 4; ++n) {
        const int dglob = (n0 - 2 * CDIM) + wc * 64 + n * 16 + ln;
        bf16x4 w;
        #pragma unroll
        for (int r = 0; r < 4; ++r) w[r] = (bf16)acc[m][n][r];
        *(bf16x4*)(Vt + (size_t)(b * CDIM + dglob) * SEQ + npos) = w;
      }
    }
  } else {
    #pragma unroll
    for (int m = 0; m < 4; ++m) {
      int rowb = m0 + wr * 64 + m * 16 + g * 4;
      #pragma unroll
      for (int n = 0; n < 4; ++n) {
        int col = n0 + wc * 64 + n * 16 + ln;
        float bv = OUT_F32 ? bias[col] : 0.f;
        #pragma unroll
        for (int r = 0; r < 4; ++r) {
          if (OUT_F32)
            ((float*)Cout)[(size_t)(rowb + r) * Nn + col] = acc[m][n][r] + bv;
          else
            ((bf16*)Cout)[(size_t)(rowb + r) * Nn + col] = (bf16)acc[m][n][r];
        }
      }
    }
  }
}

// ---------------- flash attention fwd (R18, 3-buf single-barrier: 138us) --
__global__ __launch_bounds__(512, 4)
void attn_fwd13(const bf16* __restrict__ qkv, const bf16* __restrict__ Vt,
                bf16* __restrict__ Oa) {
  __shared__ bf16 Ks[3][4096];
  __shared__ bf16 Vs[3][4096];
  const int tid = threadIdx.x, wid = tid >> 6, lane = tid & 63;
  const int g = lane >> 4, ln = lane & 15;
  const int qt = blockIdx.x, bh = blockIdx.y;
  const int b = bh / NHEAD, h = bh % NHEAD;

  const bf16* QrowA = qkv + ((size_t)b * SEQ + qt * 256 + wid * 32 + ln) * NQKV + h * DH;
  const bf16* QrowB = QrowA + (size_t)16 * NQKV;
  const bf16x8 qA0 = *(const bf16x8*)(QrowA + g * 8);
  const bf16x8 qA1 = *(const bf16x8*)(QrowA + 32 + g * 8);
  const bf16x8 qB0 = *(const bf16x8*)(QrowB + g * 8);
  const bf16x8 qB1 = *(const bf16x8*)(QrowB + 32 + g * 8);

  const int sr = lane >> 3, sl = lane & 7;
  const int pr = wid * 8 + sr;
  const int sw = (sl ^ (pr & 7)) << 3;
  const int keyK = ((pr >> 5) & 1) * 32 + ((pr >> 4) & 1) * 4 + ((pr >> 2) & 3) * 8 + (pr & 3);
  const bf16* kp = qkv + ((size_t)b * SEQ + keyK) * NQKV + CDIM + h * DH + sw;
  const bf16* vp = Vt + ((size_t)bh * DH + pr) * SEQ + sw;
  const int lofs = wid * 512;
  const size_t KADV = (size_t)64 * NQKV;

  const int e7 = ln & 7;
  const int off0 = ln * 64 + ((g ^ e7) << 3);
  const int off1 = ln * 64 + (((4 | g) ^ e7) << 3);

  const bf16 one = (bf16)1.0f;
  const bf16x8 onesF = {one, one, one, one, one, one, one, one};

  f32x4 oA[4] = {}, oB[4] = {};
  f32x4 laccA = {0.f, 0.f, 0.f, 0.f}, laccB = {0.f, 0.f, 0.f, 0.f};
  float mA = -3.0e38f, mB = -3.0e38f;
  const float SC = 0.125f * 1.44269504088896f;

  gload_lds16(kp, &Ks[0][lofs]);
  gload_lds16(vp, &Vs[0][lofs]);
  kp += KADV; vp += 64;
  gload_lds16(kp, &Ks[1][lofs]);
  gload_lds16(vp, &Vs[1][lofs]);
  kp += KADV; vp += 64;

  const int NT = SEQ / 64;
  int cur = 0;
  for (int t = 0; t < NT; ++t) {
    if (t == NT - 1) asm volatile("s_waitcnt vmcnt(0)" ::: "memory");
    else             asm volatile("s_waitcnt vmcnt(2)" ::: "memory");
    __builtin_amdgcn_s_barrier();
    __builtin_amdgcn_sched_barrier(0);

    if (t + 2 < NT) {
      int sb = cur + 2; if (sb >= 3) sb -= 3;
      gload_lds16(kp, &Ks[sb][lofs]);
      gload_lds16(vp, &Vs[sb][lofs]);
      kp += KADV; vp += 64;
    }

    const bf16* KsB = &Ks[cur][0];
    const bf16* VsB = &Vs[cur][0];

    f32x4 sA[4] = {}, sB[4] = {};
    #pragma unroll
    for (int nt = 0; nt < 4; ++nt) {
      bf16x8 kF0 = *(const bf16x8*)(KsB + off0 + nt * 1024);
      bf16x8 kF1 = *(const bf16x8*)(KsB + off1 + nt * 1024);
      sA[nt] = mfma16(kF0, qA0, sA[nt]);
      sA[nt] = mfma16(kF1, qA1, sA[nt]);
      sB[nt] = mfma16(kF0, qB0, sB[nt]);
      sB[nt] = mfma16(kF1, qB1, sB[nt]);
    }

    float a0 = fmaxf(fmaxf(sA[0][0], sA[0][1]), fmaxf(sA[0][2], sA[0][3]));
    float a1 = fmaxf(fmaxf(sA[1][0], sA[1][1]), fmaxf(sA[1][2], sA[1][3]));
    float a2 = fmaxf(fmaxf(sA[2][0], sA[2][1]), fmaxf(sA[2][2], sA[2][3]));
    float a3 = fmaxf(fmaxf(sA[3][0], sA[3][1]), fmaxf(sA[3][2], sA[3][3]));
    float rA = fmaxf(fmaxf(a0, a1), fmaxf(a2, a3));
    rA = fmaxf(rA, __shfl_xor(rA, 16, 64));
    rA = fmaxf(rA, __shfl_xor(rA, 32, 64));
    float b0 = fmaxf(fmaxf(sB[0][0], sB[0][1]), fmaxf(sB[0][2], sB[0][3]));
    float b1 = fmaxf(fmaxf(sB[1][0], sB[1][1]), fmaxf(sB[1][2], sB[1][3]));
    float b2 = fmaxf(fmaxf(sB[2][0], sB[2][1]), fmaxf(sB[2][2], sB[2][3]));
    float b3 = fmaxf(fmaxf(sB[3][0], sB[3][1]), fmaxf(sB[3][2], sB[3][3]));
    float rB = fmaxf(fmaxf(b0, b1), fmaxf(b2, b3));
    rB = fmaxf(rB, __shfl_xor(rB, 16, 64));
    rB = fmaxf(rB, __shfl_xor(rB, 32, 64));
    const float rsA = rA * SC, rsB = rB * SC;

    if (__any(rsA > mA + 8.0f || rsB > mB + 8.0f)) {
      float nmA = fmaxf(mA, rsA), nmB = fmaxf(mB, rsB);
      float alA = exp2_raw(mA - nmA), alB = exp2_raw(mB - nmB);
      mA = nmA; mB = nmB;
      float alrA[4], alrB[4];
      #pragma unroll
      for (int r = 0; r < 4; ++r) {
        alrA[r] = __shfl(alA, g * 4 + r, 64);
        alrB[r] = __shfl(alB, g * 4 + r, 64);
      }
      #pragma unroll
      for (int dt = 0; dt < 4; ++dt)
        #pragma unroll
        for (int r = 0; r < 4; ++r) { oA[dt][r] *= alrA[r]; oB[dt][r] *= alrB[r]; }
      #pragma unroll
      for (int r = 0; r < 4; ++r) { laccA[r] *= alrA[r]; laccB[r] *= alrB[r]; }
    }

    bf16x8 pA[2], pB[2];
    #pragma unroll
    for (int kk = 0; kk < 2; ++kk) {
      union { bf16x8 v; unsigned u[4]; } w;
      w.u[0] = cvt_pk_bf16(exp2_raw(fmaf(sA[2*kk][0], SC, -mA)),
                           exp2_raw(fmaf(sA[2*kk][1], SC, -mA)));
      w.u[1] = cvt_pk_bf16(exp2_raw(fmaf(sA[2*kk][2], SC, -mA)),
                           exp2_raw(fmaf(sA[2*kk][3], SC, -mA)));
      w.u[2] = cvt_pk_bf16(exp2_raw(fmaf(sA[2*kk+1][0], SC, -mA)),
                           exp2_raw(fmaf(sA[2*kk+1][1], SC, -mA)));
      w.u[3] = cvt_pk_bf16(exp2_raw(fmaf(sA[2*kk+1][2], SC, -mA)),
                           exp2_raw(fmaf(sA[2*kk+1][3], SC, -mA)));
      pA[kk] = w.v;
      w.u[0] = cvt_pk_bf16(exp2_raw(fmaf(sB[2*kk][0], SC, -mB)),
                           exp2_raw(fmaf(sB[2*kk][1], SC, -mB)));
      w.u[1] = cvt_pk_bf16(exp2_raw(fmaf(sB[2*kk][2], SC, -mB)),
                           exp2_raw(fmaf(sB[2*kk][3], SC, -mB)));
      w.u[2] = cvt_pk_bf16(exp2_raw(fmaf(sB[2*kk+1][0], SC, -mB)),
                           exp2_raw(fmaf(sB[2*kk+1][1], SC, -mB)));
      w.u[3] = cvt_pk_bf16(exp2_raw(fmaf(sB[2*kk+1][2], SC, -mB)),
                           exp2_raw(fmaf(sB[2*kk+1][3], SC, -mB)));
      pB[kk] = w.v;
    }

    #pragma unroll
    for (int kk = 0; kk < 2; ++kk) {
      laccA = mfma16(pA[kk], onesF, laccA);
      laccB = mfma16(pB[kk], onesF, laccB);
      const int voff = kk ? off1 : off0;
      #pragma unroll
      for (int dt = 0; dt < 4; ++dt) {
        bf16x8 vF = *(const bf16x8*)(VsB + voff + dt * 1024);
        oA[dt] = mfma16(pA[kk], vF, oA[dt]);
        oB[dt] = mfma16(pB[kk], vF, oB[dt]);
      }
    }

    cur = (cur + 1 == 3) ? 0 : cur + 1;
  }

  float invA[4], invB[4];
  #pragma unroll
  for (int r = 0; r < 4; ++r) { invA[r] = 1.0f / laccA[r]; invB[r] = 1.0f / laccB[r]; }

  #pragma unroll
  for (int r = 0; r < 4; ++r) {
    bf16* OrA = Oa + ((size_t)b * SEQ + qt * 256 + wid * 32 + g * 4 + r) * CDIM + h * DH + ln;
    bf16* OrB = OrA + (size_t)16 * CDIM;
    #pragma unroll
    for (int dt = 0; dt < 4; ++dt) {
      OrA[dt * 16] = (bf16)(oA[dt][r] * invA[r]);
      OrB[dt * 16] = (bf16)(oB[dt][r] * invB[r]);
    }
  }
}

// ---------------- launch --------------------------------------------------
extern "C" void kernel_launch(void* const* d_in, const int* in_sizes, int n_in,
                              void* d_out, int out_size, void* d_ws, size_t ws_size,
                              hipStream_t stream) {
  const float* x      = (const float*)d_in[0];
  const float* w_qkv  = (const float*)d_in[1];
  const float* w_proj = (const float*)d_in[2];
  const float* b_proj = (const float*)d_in[3];

  char* ws = (char*)d_ws;
  bf16* x_bf    = (bf16*)(ws + 0);                    // 25165824
  bf16* wqkv_bf = (bf16*)(ws + 25165824);             // 3538944
  bf16* wproj_bf= (bf16*)(ws + 28704768);             // 1179648
  bf16* qkv     = (bf16*)(ws + 29884416);             // 75497472
  bf16* attn_o  = (bf16*)(ws + 105381888);            // 25165824
  bf16* Vtb     = (bf16*)(ws + 130547712);            // 25165824

  cvt_all<<<dim3(7296), 256, 0, stream>>>(x, w_qkv, w_proj, x_bf, wqkv_bf, wproj_bf);

  gemm_bt<0><<<dim3((MROWS/128)*(NQKV/128)), 256, 0, stream>>>(
      x_bf, wqkv_bf, qkv, nullptr, Vtb, MROWS, NQKV, CDIM);

  attn_fwd13<<<dim3(SEQ/256, NBATCH*NHEAD), 512, 0, stream>>>(qkv, Vtb, attn_o);

  gemm_bt<1><<<dim3((MROWS/128)*(CDIM/128)), 256, 0, stream>>>(
      attn_o, wproj_bf, (float*)d_out, b_proj, nullptr, MROWS, CDIM, CDIM);
}

// Round 20
// 250.207 us; speedup vs baseline: 1.0092x; 1.0092x over previous
//
#include <hip/hip_runtime.h>

typedef __bf16 bf16;
typedef __attribute__((ext_vector_type(8))) __bf16 bf16x8;
typedef __attribute__((ext_vector_type(4))) __bf16 bf16x4;
typedef __attribute__((ext_vector_type(4))) float f32x4;

#define NBATCH 8
#define NHEAD  12
#define SEQ    2048
#define DH     64
#define CDIM   768
#define MROWS  (NBATCH*SEQ)   /* 16384 */
#define NQKV   (3*CDIM)       /* 2304  */

__device__ __forceinline__ f32x4 mfma16(bf16x8 a, bf16x8 b, f32x4 c) {
  return __builtin_amdgcn_mfma_f32_16x16x32_bf16(a, b, c, 0, 0, 0);
}

__device__ __forceinline__ void gload_lds16(const void* g, void* l) {
  __builtin_amdgcn_global_load_lds((const __attribute__((address_space(1))) void*)g,
                                   (__attribute__((address_space(3))) void*)l,
                                   16, 0, 0);
}

// pack 2 f32 -> 1 u32 of 2 bf16 (T12; no builtin on gfx950, guide m240)
__device__ __forceinline__ unsigned cvt_pk_bf16(float lo, float hi) {
  unsigned r;
  asm("v_cvt_pk_bf16_f32 %0, %1, %2" : "=v"(r) : "v"(lo), "v"(hi));
  return r;
}

// raw v_exp_f32 (2^x). Register-only asm; args always <= 0 after first rescale.
__device__ __forceinline__ float exp2_raw(float x) {
  float r;
  asm("v_exp_f32 %0, %1" : "=v"(r) : "v"(x));
  return r;
}

// ---------------- fp32 -> bf16 convert (all three inputs, one launch) -----
__global__ __launch_bounds__(256)
void cvt_all(const float* __restrict__ x, const float* __restrict__ wq,
             const float* __restrict__ wp, bf16* __restrict__ xd,
             bf16* __restrict__ wqd, bf16* __restrict__ wpd) {
  const int bid = blockIdx.x;
  const float* s;
  bf16* d;
  int i;
  if (bid < 6144)      { s = x;  d = xd;  i = bid * 256 + threadIdx.x; }
  else if (bid < 7008) { s = wq; d = wqd; i = (bid - 6144) * 256 + threadIdx.x; }
  else                 { s = wp; d = wpd; i = (bid - 7008) * 256 + threadIdx.x; }
  const float4* s4 = (const float4*)s;
  float4 a = s4[2*i], c = s4[2*i+1];
  bf16x8 o;
  o[0]=(bf16)a.x; o[1]=(bf16)a.y; o[2]=(bf16)a.z; o[3]=(bf16)a.w;
  o[4]=(bf16)c.x; o[5]=(bf16)c.y; o[6]=(bf16)c.z; o[7]=(bf16)c.w;
  *(bf16x8*)(d + (size_t)i*8) = o;
}

// ---------------- GEMM 128x128 / BK=32, 3-buf single-barrier pipeline -----
// R18 best config (gsz=32 restored after R19's 16-tile group regressed).
// V-section tiles (n0>=1536) write transposed into Vt (R17 fusion, proven).
template <int OUT_F32>
__global__ __launch_bounds__(256, 3)
void gemm_bt(const bf16* __restrict__ A, const bf16* __restrict__ Bm,
             void* __restrict__ Cout, const float* __restrict__ bias,
             bf16* __restrict__ Vt, int M, int Nn, int K) {
  __shared__ bf16 As[3][4096];
  __shared__ bf16 Bs[3][4096];
  const int tid = threadIdx.x, wid = tid >> 6, lane = tid & 63;
  const int g = lane >> 4, ln = lane & 15;
  const int ntn = Nn >> 7;
  const int gsz = 32 * ntn;
  const int grp = blockIdx.x / gsz;
  const int rem = blockIdx.x - grp * gsz;
  const int tm = grp * 32 + (rem & 31);
  const int tn = rem >> 5;
  const int m0 = tm << 7, n0 = tn << 7;
  const int wr = wid >> 1, wc = wid & 1;

  const int srow = lane >> 2;
  const int sslot = lane & 3;
  const int c0 = wid * 2, c1 = wid * 2 + 1;
  const int row0 = c0 * 16 + srow, row1 = c1 * 16 + srow;
  const int sw0 = (sslot ^ (row0 & 3)) << 3;
  const int sw1 = (sslot ^ (row1 & 3)) << 3;
  const bf16* a0 = A + (size_t)(m0 + row0) * K + sw0;
  const bf16* a1 = A + (size_t)(m0 + row1) * K + sw1;
  const bf16* b0 = Bm + (size_t)(n0 + row0) * K + sw0;
  const bf16* b1 = Bm + (size_t)(n0 + row1) * K + sw1;

  f32x4 acc[4][4] = {};
  const int nkt = K >> 5;

#define GSTAGE(BUF) do {                                          \
    gload_lds16(a0, &As[BUF][c0 * 512]);                          \
    gload_lds16(a1, &As[BUF][c1 * 512]);                          \
    gload_lds16(b0, &Bs[BUF][c0 * 512]);                          \
    gload_lds16(b1, &Bs[BUF][c1 * 512]);                          \
    a0 += 32; a1 += 32; b0 += 32; b1 += 32;                       \
  } while (0)

  GSTAGE(0);
  GSTAGE(1);

  int cur = 0;
  for (int kt = 0; kt < nkt; ++kt) {
    if (kt < nkt - 1) asm volatile("s_waitcnt vmcnt(4)" ::: "memory");
    else              asm volatile("s_waitcnt vmcnt(0)" ::: "memory");
    __builtin_amdgcn_s_barrier();
    __builtin_amdgcn_sched_barrier(0);

    if (kt + 2 < nkt) {
      int sb = cur + 2; if (sb >= 3) sb -= 3;
      GSTAGE(sb);
    }

    const bf16* AsB = &As[cur][0];
    const bf16* BsB = &Bs[cur][0];
    bf16x8 aF[4], bF[4];
    #pragma unroll
    for (int m = 0; m < 4; ++m) {
      int row = wr * 64 + m * 16 + ln;
      aF[m] = *(const bf16x8*)&AsB[row * 32 + ((g ^ (row & 3)) << 3)];
    }
    #pragma unroll
    for (int n = 0; n < 4; ++n) {
      int row = wc * 64 + n * 16 + ln;
      bF[n] = *(const bf16x8*)&BsB[row * 32 + ((g ^ (row & 3)) << 3)];
    }
    #pragma unroll
    for (int m = 0; m < 4; ++m)
      #pragma unroll
      for (int n = 0; n < 4; ++n)
        acc[m][n] = mfma16(aF[m], bF[n], acc[m][n]);

    cur = (cur + 1 == 3) ? 0 : cur + 1;
  }
#undef GSTAGE

  if (!OUT_F32 && n0 >= 2 * CDIM) {
    // V-tile: write transposed into Vt [b*768 + dglobal][npos] (stride SEQ)
    const int b = m0 >> 11;
    const int npos0 = m0 & (SEQ - 1);
    #pragma unroll
    for (int m = 0; m < 4; ++m) {
      const int npos = npos0 + wr * 64 + m * 16 + g * 4;
      #pragma unroll
      for (int n = 0; n < 4; ++n) {
        const int dglob = (n0 - 2 * CDIM) + wc * 64 + n * 16 + ln;
        bf16x4 w;
        #pragma unroll
        for (int r = 0; r < 4; ++r) w[r] = (bf16)acc[m][n][r];
        *(bf16x4*)(Vt + (size_t)(b * CDIM + dglob) * SEQ + npos) = w;
      }
    }
  } else {
    #pragma unroll
    for (int m = 0; m < 4; ++m) {
      int rowb = m0 + wr * 64 + m * 16 + g * 4;
      #pragma unroll
      for (int n = 0; n < 4; ++n) {
        int col = n0 + wc * 64 + n * 16 + ln;
        float bv = OUT_F32 ? bias[col] : 0.f;
        #pragma unroll
        for (int r = 0; r < 4; ++r) {
          if (OUT_F32)
            ((float*)Cout)[(size_t)(rowb + r) * Nn + col] = acc[m][n][r] + bv;
          else
            ((bf16*)Cout)[(size_t)(rowb + r) * Nn + col] = (bf16)acc[m][n][r];
        }
      }
    }
  }
}

// ---------------- flash attention fwd (R18, 3-buf single-barrier: 138us) --
__global__ __launch_bounds__(512, 4)
void attn_fwd13(const bf16* __restrict__ qkv, const bf16* __restrict__ Vt,
                bf16* __restrict__ Oa) {
  __shared__ bf16 Ks[3][4096];
  __shared__ bf16 Vs[3][4096];
  const int tid = threadIdx.x, wid = tid >> 6, lane = tid & 63;
  const int g = lane >> 4, ln = lane & 15;
  const int qt = blockIdx.x, bh = blockIdx.y;
  const int b = bh / NHEAD, h = bh % NHEAD;

  const bf16* QrowA = qkv + ((size_t)b * SEQ + qt * 256 + wid * 32 + ln) * NQKV + h * DH;
  const bf16* QrowB = QrowA + (size_t)16 * NQKV;
  const bf16x8 qA0 = *(const bf16x8*)(QrowA + g * 8);
  const bf16x8 qA1 = *(const bf16x8*)(QrowA + 32 + g * 8);
  const bf16x8 qB0 = *(const bf16x8*)(QrowB + g * 8);
  const bf16x8 qB1 = *(const bf16x8*)(QrowB + 32 + g * 8);

  const int sr = lane >> 3, sl = lane & 7;
  const int pr = wid * 8 + sr;
  const int sw = (sl ^ (pr & 7)) << 3;
  const int keyK = ((pr >> 5) & 1) * 32 + ((pr >> 4) & 1) * 4 + ((pr >> 2) & 3) * 8 + (pr & 3);
  const bf16* kp = qkv + ((size_t)b * SEQ + keyK) * NQKV + CDIM + h * DH + sw;
  const bf16* vp = Vt + ((size_t)bh * DH + pr) * SEQ + sw;
  const int lofs = wid * 512;
  const size_t KADV = (size_t)64 * NQKV;

  const int e7 = ln & 7;
  const int off0 = ln * 64 + ((g ^ e7) << 3);
  const int off1 = ln * 64 + (((4 | g) ^ e7) << 3);

  const bf16 one = (bf16)1.0f;
  const bf16x8 onesF = {one, one, one, one, one, one, one, one};

  f32x4 oA[4] = {}, oB[4] = {};
  f32x4 laccA = {0.f, 0.f, 0.f, 0.f}, laccB = {0.f, 0.f, 0.f, 0.f};
  float mA = -3.0e38f, mB = -3.0e38f;
  const float SC = 0.125f * 1.44269504088896f;

  gload_lds16(kp, &Ks[0][lofs]);
  gload_lds16(vp, &Vs[0][lofs]);
  kp += KADV; vp += 64;
  gload_lds16(kp, &Ks[1][lofs]);
  gload_lds16(vp, &Vs[1][lofs]);
  kp += KADV; vp += 64;

  const int NT = SEQ / 64;
  int cur = 0;
  for (int t = 0; t < NT; ++t) {
    if (t == NT - 1) asm volatile("s_waitcnt vmcnt(0)" ::: "memory");
    else             asm volatile("s_waitcnt vmcnt(2)" ::: "memory");
    __builtin_amdgcn_s_barrier();
    __builtin_amdgcn_sched_barrier(0);

    if (t + 2 < NT) {
      int sb = cur + 2; if (sb >= 3) sb -= 3;
      gload_lds16(kp, &Ks[sb][lofs]);
      gload_lds16(vp, &Vs[sb][lofs]);
      kp += KADV; vp += 64;
    }

    const bf16* KsB = &Ks[cur][0];
    const bf16* VsB = &Vs[cur][0];

    f32x4 sA[4] = {}, sB[4] = {};
    #pragma unroll
    for (int nt = 0; nt < 4; ++nt) {
      bf16x8 kF0 = *(const bf16x8*)(KsB + off0 + nt * 1024);
      bf16x8 kF1 = *(const bf16x8*)(KsB + off1 + nt * 1024);
      sA[nt] = mfma16(kF0, qA0, sA[nt]);
      sA[nt] = mfma16(kF1, qA1, sA[nt]);
      sB[nt] = mfma16(kF0, qB0, sB[nt]);
      sB[nt] = mfma16(kF1, qB1, sB[nt]);
    }

    float a0 = fmaxf(fmaxf(sA[0][0], sA[0][1]), fmaxf(sA[0][2], sA[0][3]));
    float a1 = fmaxf(fmaxf(sA[1][0], sA[1][1]), fmaxf(sA[1][2], sA[1][3]));
    float a2 = fmaxf(fmaxf(sA[2][0], sA[2][1]), fmaxf(sA[2][2], sA[2][3]));
    float a3 = fmaxf(fmaxf(sA[3][0], sA[3][1]), fmaxf(sA[3][2], sA[3][3]));
    float rA = fmaxf(fmaxf(a0, a1), fmaxf(a2, a3));
    rA = fmaxf(rA, __shfl_xor(rA, 16, 64));
    rA = fmaxf(rA, __shfl_xor(rA, 32, 64));
    float b0 = fmaxf(fmaxf(sB[0][0], sB[0][1]), fmaxf(sB[0][2], sB[0][3]));
    float b1 = fmaxf(fmaxf(sB[1][0], sB[1][1]), fmaxf(sB[1][2], sB[1][3]));
    float b2 = fmaxf(fmaxf(sB[2][0], sB[2][1]), fmaxf(sB[2][2], sB[2][3]));
    float b3 = fmaxf(fmaxf(sB[3][0], sB[3][1]), fmaxf(sB[3][2], sB[3][3]));
    float rB = fmaxf(fmaxf(b0, b1), fmaxf(b2, b3));
    rB = fmaxf(rB, __shfl_xor(rB, 16, 64));
    rB = fmaxf(rB, __shfl_xor(rB, 32, 64));
    const float rsA = rA * SC, rsB = rB * SC;

    if (__any(rsA > mA + 8.0f || rsB > mB + 8.0f)) {
      float nmA = fmaxf(mA, rsA), nmB = fmaxf(mB, rsB);
      float alA = exp2_raw(mA - nmA), alB = exp2_raw(mB - nmB);
      mA = nmA; mB = nmB;
      float alrA[4], alrB[4];
      #pragma unroll
      for (int r = 0; r < 4; ++r) {
        alrA[r] = __shfl(alA, g * 4 + r, 64);
        alrB[r] = __shfl(alB, g * 4 + r, 64);
      }
      #pragma unroll
      for (int dt = 0; dt < 4; ++dt)
        #pragma unroll
        for (int r = 0; r < 4; ++r) { oA[dt][r] *= alrA[r]; oB[dt][r] *= alrB[r]; }
      #pragma unroll
      for (int r = 0; r < 4; ++r) { laccA[r] *= alrA[r]; laccB[r] *= alrB[r]; }
    }

    bf16x8 pA[2], pB[2];
    #pragma unroll
    for (int kk = 0; kk < 2; ++kk) {
      union { bf16x8 v; unsigned u[4]; } w;
      w.u[0] = cvt_pk_bf16(exp2_raw(fmaf(sA[2*kk][0], SC, -mA)),
                           exp2_raw(fmaf(sA[2*kk][1], SC, -mA)));
      w.u[1] = cvt_pk_bf16(exp2_raw(fmaf(sA[2*kk][2], SC, -mA)),
                           exp2_raw(fmaf(sA[2*kk][3], SC, -mA)));
      w.u[2] = cvt_pk_bf16(exp2_raw(fmaf(sA[2*kk+1][0], SC, -mA)),
                           exp2_raw(fmaf(sA[2*kk+1][1], SC, -mA)));
      w.u[3] = cvt_pk_bf16(exp2_raw(fmaf(sA[2*kk+1][2], SC, -mA)),
                           exp2_raw(fmaf(sA[2*kk+1][3], SC, -mA)));
      pA[kk] = w.v;
      w.u[0] = cvt_pk_bf16(exp2_raw(fmaf(sB[2*kk][0], SC, -mB)),
                           exp2_raw(fmaf(sB[2*kk][1], SC, -mB)));
      w.u[1] = cvt_pk_bf16(exp2_raw(fmaf(sB[2*kk][2], SC, -mB)),
                           exp2_raw(fmaf(sB[2*kk][3], SC, -mB)));
      w.u[2] = cvt_pk_bf16(exp2_raw(fmaf(sB[2*kk+1][0], SC, -mB)),
                           exp2_raw(fmaf(sB[2*kk+1][1], SC, -mB)));
      w.u[3] = cvt_pk_bf16(exp2_raw(fmaf(sB[2*kk+1][2], SC, -mB)),
                           exp2_raw(fmaf(sB[2*kk+1][3], SC, -mB)));
      pB[kk] = w.v;
    }

    #pragma unroll
    for (int kk = 0; kk < 2; ++kk) {
      laccA = mfma16(pA[kk], onesF, laccA);
      laccB = mfma16(pB[kk], onesF, laccB);
      const int voff = kk ? off1 : off0;
      #pragma unroll
      for (int dt = 0; dt < 4; ++dt) {
        bf16x8 vF = *(const bf16x8*)(VsB + voff + dt * 1024);
        oA[dt] = mfma16(pA[kk], vF, oA[dt]);
        oB[dt] = mfma16(pB[kk], vF, oB[dt]);
      }
    }

    cur = (cur + 1 == 3) ? 0 : cur + 1;
  }

  float invA[4], invB[4];
  #pragma unroll
  for (int r = 0; r < 4; ++r) { invA[r] = 1.0f / laccA[r]; invB[r] = 1.0f / laccB[r]; }

  #pragma unroll
  for (int r = 0; r < 4; ++r) {
    bf16* OrA = Oa + ((size_t)b * SEQ + qt * 256 + wid * 32 + g * 4 + r) * CDIM + h * DH + ln;
    bf16* OrB = OrA + (size_t)16 * CDIM;
    #pragma unroll
    for (int dt = 0; dt < 4; ++dt) {
      OrA[dt * 16] = (bf16)(oA[dt][r] * invA[r]);
      OrB[dt * 16] = (bf16)(oB[dt][r] * invB[r]);
    }
  }
}

// ---------------- launch --------------------------------------------------
extern "C" void kernel_launch(void* const* d_in, const int* in_sizes, int n_in,
                              void* d_out, int out_size, void* d_ws, size_t ws_size,
                              hipStream_t stream) {
  const float* x      = (const float*)d_in[0];
  const float* w_qkv  = (const float*)d_in[1];
  const float* w_proj = (const float*)d_in[2];
  const float* b_proj = (const float*)d_in[3];

  char* ws = (char*)d_ws;
  bf16* x_bf    = (bf16*)(ws + 0);                    // 25165824
  bf16* wqkv_bf = (bf16*)(ws + 25165824);             // 3538944
  bf16* wproj_bf= (bf16*)(ws + 28704768);             // 1179648
  bf16* qkv     = (bf16*)(ws + 29884416);             // 75497472
  bf16* attn_o  = (bf16*)(ws + 105381888);            // 25165824
  bf16* Vtb     = (bf16*)(ws + 130547712);            // 25165824

  cvt_all<<<dim3(7296), 256, 0, stream>>>(x, w_qkv, w_proj, x_bf, wqkv_bf, wproj_bf);

  gemm_bt<0><<<dim3((MROWS/128)*(NQKV/128)), 256, 0, stream>>>(
      x_bf, wqkv_bf, qkv, nullptr, Vtb, MROWS, NQKV, CDIM);

  attn_fwd13<<<dim3(SEQ/256, NBATCH*NHEAD), 512, 0, stream>>>(qkv, Vtb, attn_o);

  gemm_bt<1><<<dim3((MROWS/128)*(CDIM/128)), 256, 0, stream>>>(
      attn_o, wproj_bf, (float*)d_out, b_proj, nullptr, MROWS, CDIM, CDIM);
}